// Round 9
// baseline (65.600 us; speedup 1.0000x reference)
//
#include <hip/hip_runtime.h>

// out[b, t, w, c] = x[b, t + w - 9, c] (zero outside [0, T)), x: [32, 4096, 30] f32.
// R3-R8 established: pinned at ~56us regardless of store width/policy/MLP/
// stream-length/XCD-swizzle. Accounting: 299MB writes + 299MB cache-served
// reads = 10.6 TB/s combined fabric vs fill's 6.9 TB/s pure-write -> theory:
// read amplification shares the fabric with the write stream. This round:
// LDS staging kills the 19x read reuse against global. Each block owns 128
// output rows of one batch; its input is ONE contiguous 4380-float span
// (rows t0-9 .. t0+136, 17.5KB LDS). Fabric traffic 598 -> ~317MB.

typedef float f32x4 __attribute__((ext_vector_type(4)));

constexpr int B   = 32;
constexpr int T   = 4096;
constexpr int C   = 30;
constexpr int PAD = 9;              // W/2
constexpr int ROW = 570;            // W*C floats per output row
constexpr int TC  = T * C;          // 122880 floats per batch of x
constexpr int TB  = 128;            // output rows per block
constexpr int SROWS   = TB + 2 * PAD;      // 146 staged x rows
constexpr int SFLOATS = SROWS * C;         // 4380 floats = 17,520 B LDS
constexpr int S2      = SFLOATS / 2;       // 2190 float2 staging units
constexpr int OUT_F4  = TB / 2 * 285;      // 18,240 float4 units per block
constexpr unsigned NWG = (unsigned)B * (T / TB);   // 1024 blocks

__global__ __launch_bounds__(256)
void OverlapTimeWindowLayer_kernel(const float* __restrict__ x,
                                   f32x4* __restrict__ out) {
    __shared__ float lds[SFLOATS];

    const unsigned blk = blockIdx.x;
    const int b  = (int)(blk >> 5);          // 32 blocks per batch (4096/128)
    const int t0 = (int)(blk & 31u) * TB;
    const float* xb = x + (unsigned)b * TC;
    const int sbase = (t0 - PAD) * C;        // float offset of lds[0] in batch
                                             // (always even: multiple of 30)

    // ---- Stage: one contiguous span, zero-padded at batch edges ----
    for (int j = (int)threadIdx.x; j < S2; j += 256) {
        const int s = sbase + 2 * j;         // even; 0 and TC even -> one check
        float2 v = make_float2(0.0f, 0.0f);
        if (s >= 0 && s < TC) v = *reinterpret_cast<const float2*>(xb + s);
        *reinterpret_cast<float2*>(lds + 2 * j) = v;
    }
    __syncthreads();

    // ---- Emit: 292KB contiguous tile, lane-coalesced 16B NT stores ----
    // Output row t = lds[(t-t0)*30 .. +570). Row-pair rp (rows 2rp, 2rp+1):
    // element e of pair maps to lds float (2rp)*30 + e - (e>=570 ? 540 : 0).
    f32x4* outb = out + blk * (unsigned)OUT_F4;
#pragma unroll 2
    for (int i = (int)threadIdx.x; i < OUT_F4; i += 256) {
        const int rp = i / 285;              // magic-mul div
        const int u  = i - rp * 285;
        const int e0 = 4 * u;
        const int f  = rp * 60 + e0;         // (2rp)*30 + e0
        const int f0 = f     - (e0     >= ROW ? (ROW - C) : 0);
        const int f1 = f + 2 - (e0 + 2 >= ROW ? (ROW - C) : 0);

        const float2 lo = *reinterpret_cast<const float2*>(lds + f0);
        const float2 hi = *reinterpret_cast<const float2*>(lds + f1);

        f32x4 val;
        val.x = lo.x; val.y = lo.y; val.z = hi.x; val.w = hi.y;
        __builtin_nontemporal_store(val, outb + i);
    }
}

extern "C" void kernel_launch(void* const* d_in, const int* in_sizes, int n_in,
                              void* d_out, int out_size, void* d_ws, size_t ws_size,
                              hipStream_t stream) {
    const float* x = (const float*)d_in[0];
    f32x4* out = (f32x4*)d_out;
    OverlapTimeWindowLayer_kernel<<<NWG, 256, 0, stream>>>(x, out);
}